// Round 8
// baseline (114.270 us; speedup 1.0000x reference)
//
#include <hip/hip_runtime.h>
#include <hip/hip_bf16.h>

#define BATCH 16
#define HH 384
#define WW 384
#define CINC 16
#define FOUT 32
#define BY 8                    // output rows per block
#define TR 10                   // LDS tile rows (BY + 2 halo)
#define TC 66                   // LDS tile cols (64 + 2 halo)
#define LDSE (TR * TC * CINC)   // 10560 bf16 = 21120 B -> ~7 blocks/CU
#define NCHUNK (LDSE / 4)       // 2640 chunks of 4 elems (16B load / 8B LDS write)
#define NSLOT 11                // 11*256 = 2816 >= 2640

typedef __bf16 bf16x8 __attribute__((ext_vector_type(8)));
typedef __bf16 bf16x4 __attribute__((ext_vector_type(4)));
typedef float f32x4 __attribute__((ext_vector_type(4)));

// Effective weight W[f][c][ky][kx] = ws + wsilu; tap = ky*3+kx.
// A fragment (weights) for mfma_f32_16x16x32_bf16: row i = lane&15,
// k = (lane>>4)*8 + e. K=32 packs 2 taps x 16 ch.
__device__ inline bf16x8 compute_afrag(const float* ws, const float* wsilu,
                                       int s, int nt, int lane) {
    int f   = (lane & 15) + 16 * nt;
    int kb  = lane >> 4;
    int tap = 2 * s + (kb >> 1);   // s=4,kb>=2 -> tap 9 (pad -> zero)
    int cb  = (kb & 1) * 8;
    bf16x8 r;
#pragma unroll
    for (int e = 0; e < 8; ++e) {
        float v = 0.f;
        if (tap < 9) {
            int idx = f * (CINC * 9) + (cb + e) * 9 + tap;
            v = ws[idx] + wsilu[idx];
        }
        r[e] = (__bf16)v;
    }
    return r;
}

__global__ void prep_weights(const float* __restrict__ ws, const float* __restrict__ wsilu,
                             bf16x8* __restrict__ table) {
    int tid = blockIdx.x * blockDim.x + threadIdx.x;
    if (tid >= 5 * 2 * 64) return;
    int lane = tid & 63;
    int nt   = (tid >> 6) & 1;
    int s    = tid >> 7;
    table[tid] = compute_afrag(ws, wsilu, s, nt, lane);
}

// Block: 256 thr = 4 waves. Covers (b, 8-row band, 64-px strip).
// Wave wv: x-substrip wv*16, all 8 rows.
// Staging: 11 clamped loads in flight per thread, branchless (tail masked).
// Compute: row PAIRS with independent acc sets.
// Stores: PLAIN (not nontemporal) — each store instruction writes 16B chunks
// at stride 128B; L2 must write-combine them into full lines, NT bypass was
// causing HBM read-modify-write amplification (theory R7->R8).
template <bool FROMWS>
__launch_bounds__(256)
__global__ void kanconv(const float* __restrict__ x,
                        const bf16x8* __restrict__ wtab,
                        const float* __restrict__ wsp,
                        const float* __restrict__ wsi,
                        const float* __restrict__ bias,
                        float* __restrict__ out) {
    __shared__ __bf16 lds[LDSE];

    const int nblk = BATCH * (HH / BY) * (WW / 64);   // 4608, %8==0
    int id = blockIdx.x;
    id = (id & 7) * (nblk / 8) + (id >> 3);           // XCD-aware swizzle (bijective)
    const int xb = id % (WW / 64);
    const int yb = (id / (WW / 64)) % (HH / BY);
    const int b  = id / ((WW / 64) * (HH / BY));
    const int y0 = yb * BY;
    const int x0 = xb * 64;
    const int tid  = threadIdx.x;
    const int lane = tid & 63;
    const int wv   = tid >> 6;

    // ---- stage input tile: rows y0-1..y0+8, cols x0-1..x0+64, 16 ch, bf16 ----
    {
        f32x4 vv[NSLOT];
#pragma unroll
        for (int it = 0; it < NSLOT; ++it) {
            int q = tid + it * 256;
            if (q > NCHUNK - 1) q = NCHUNK - 1;       // tail: safe dup address
            const int cell = q >> 2;
            const int ch4  = q & 3;
            const int c    = cell % TC;
            const int r    = cell / TC;
            const int cy   = min(max(y0 - 1 + r, 0), HH - 1);
            const int cx   = min(max(x0 - 1 + c, 0), WW - 1);
            vv[it] = *(const f32x4*)(x + ((size_t)(b * HH + cy) * WW + cx) * CINC + ch4 * 4);
        }
#pragma unroll
        for (int it = 0; it < NSLOT; ++it) {
            const int q = tid + it * 256;
            if (it < NSLOT - 1 || q < NCHUNK) {       // static for it<10
                const int cell = q >> 2;
                const int c    = cell % TC;
                const int r    = cell / TC;
                const int gy   = y0 - 1 + r;
                const int gx   = x0 - 1 + c;
                const bool ok  = ((unsigned)gy < (unsigned)HH) && ((unsigned)gx < (unsigned)WW);
                bf16x4 h;
#pragma unroll
                for (int e = 0; e < 4; ++e) h[e] = ok ? (__bf16)vv[it][e] : (__bf16)0.f;
                *(bf16x4*)&lds[q * 4] = h;
            }
        }
    }

    // ---- weight (A) fragments, 10 per wave ----
    bf16x8 aw[5][2];
#pragma unroll
    for (int s = 0; s < 5; ++s)
#pragma unroll
        for (int nt = 0; nt < 2; ++nt) {
            if (FROMWS) aw[s][nt] = wtab[(s * 2 + nt) * 64 + lane];
            else        aw[s][nt] = compute_afrag(wsp, wsi, s, nt, lane);
        }

    const int m     = lane & 15;      // B col (pixel) / D col
    const int kb    = lane >> 4;
    const int tsel  = kb >> 1;
    const int chalf = (kb & 1) * 8;
    const int sub   = wv * 16;        // x-substrip; each wave does all 8 rows
    const int bcol  = 1 + sub + m;

    int del[5];
#pragma unroll
    for (int s = 0; s < 5; ++s) {
        int tap = 2 * s + tsel;
        if (tap > 8) tap = 8;         // pad lane: A frag is 0
        del[s] = ((tap / 3 - 1) * TC + (tap % 3 - 1)) * CINC;
    }

    const f32x4 b0 = *(const f32x4*)(bias + kb * 4);
    const f32x4 b1 = *(const f32x4*)(bias + 16 + kb * 4);

    __syncthreads();

#pragma unroll
    for (int yp = 0; yp < 4; ++yp) {
        const int yi = 2 * yp;
        const int eb1 = ((1 + yi) * TC + bcol) * CINC + chalf;
        const int eb2 = eb1 + TC * CINC;
        f32x4 a0 = b0, a1 = b1;       // row yi
        f32x4 c0 = b0, c1 = b1;       // row yi+1

#pragma unroll
        for (int s = 0; s < 5; ++s) {
            bf16x8 p1 = *(const bf16x8*)&lds[eb1 + del[s]];
            bf16x8 p2 = *(const bf16x8*)&lds[eb2 + del[s]];
            a0 = __builtin_amdgcn_mfma_f32_16x16x32_bf16(aw[s][0], p1, a0, 0, 0, 0);
            c0 = __builtin_amdgcn_mfma_f32_16x16x32_bf16(aw[s][0], p2, c0, 0, 0, 0);
            a1 = __builtin_amdgcn_mfma_f32_16x16x32_bf16(aw[s][1], p1, a1, 0, 0, 0);
            c1 = __builtin_amdgcn_mfma_f32_16x16x32_bf16(aw[s][1], p2, c1, 0, 0, 0);
        }

        // D: col = lane&15 = pixel, row = kb*4 + r = filter -> 4 consecutive ch
        const int pix = x0 + sub + m;
        float* po1 = out + (size_t)((b * HH + y0 + yi) * WW + pix) * FOUT + kb * 4;
        float* po2 = po1 + (size_t)WW * FOUT;
        *(f32x4*)po1        = a0;
        *(f32x4*)(po1 + 16) = a1;
        *(f32x4*)po2        = c0;
        *(f32x4*)(po2 + 16) = c1;
    }
}

extern "C" void kernel_launch(void* const* d_in, const int* in_sizes, int n_in,
                              void* d_out, int out_size, void* d_ws, size_t ws_size,
                              hipStream_t stream) {
    const float* x    = (const float*)d_in[0];
    const float* wsp  = (const float*)d_in[1];
    const float* wsi  = (const float*)d_in[2];
    const float* bias = (const float*)d_in[3];
    float* out        = (float*)d_out;

    const int nblk = BATCH * (HH / BY) * (WW / 64);   // 4608

    if (ws_size >= 640 * sizeof(bf16x8)) {
        bf16x8* tab = (bf16x8*)d_ws;
        prep_weights<<<3, 256, 0, stream>>>(wsp, wsi, tab);
        kanconv<true><<<nblk, 256, 0, stream>>>(x, tab, wsp, wsi, bias, out);
    } else {
        kanconv<false><<<nblk, 256, 0, stream>>>(x, nullptr, wsp, wsi, bias, out);
    }
}

// Round 9
// 73.431 us; speedup vs baseline: 1.5562x; 1.5562x over previous
//
#include <hip/hip_runtime.h>
#include <hip/hip_bf16.h>

#define BATCH 16
#define HH 384
#define WW 384
#define CINC 16
#define FOUT 32
#define BY 8                    // output rows per block
#define TR 10                   // LDS tile rows (BY + 2 halo)
#define TC 66                   // LDS tile cols (64 + 2 halo)
#define LDSE (TR * TC * CINC)   // 10560 bf16 = 21120 B
#define NCHUNK (LDSE / 4)       // 2640 chunks of 4 elems
#define NSLOT 11                // 11*256 = 2816 >= 2640

typedef __bf16 bf16x8 __attribute__((ext_vector_type(8)));
typedef __bf16 bf16x4 __attribute__((ext_vector_type(4)));
typedef float f32x4 __attribute__((ext_vector_type(4)));

// Effective weight W[f][c][ky][kx] = ws + wsilu; tap = ky*3+kx.
// A fragment (weights) for mfma_f32_16x16x32_bf16: row i = lane&15,
// k = (lane>>4)*8 + e. K=32 packs 2 taps x 16 ch.
__device__ inline bf16x8 compute_afrag(const float* ws, const float* wsilu,
                                       int s, int nt, int lane) {
    int f   = (lane & 15) + 16 * nt;
    int kb  = lane >> 4;
    int tap = 2 * s + (kb >> 1);   // s=4,kb>=2 -> tap 9 (pad -> zero)
    int cb  = (kb & 1) * 8;
    bf16x8 r;
#pragma unroll
    for (int e = 0; e < 8; ++e) {
        float v = 0.f;
        if (tap < 9) {
            int idx = f * (CINC * 9) + (cb + e) * 9 + tap;
            v = ws[idx] + wsilu[idx];
        }
        r[e] = (__bf16)v;
    }
    return r;
}

__global__ void prep_weights(const float* __restrict__ ws, const float* __restrict__ wsilu,
                             bf16x8* __restrict__ table) {
    int tid = blockIdx.x * blockDim.x + threadIdx.x;
    if (tid >= 5 * 2 * 64) return;
    int lane = tid & 63;
    int nt   = (tid >> 6) & 1;
    int s    = tid >> 7;
    table[tid] = compute_afrag(ws, wsilu, s, nt, lane);
}

// Block: 256 thr = 4 waves. Covers (b, 8-row band, 64-px strip).
// Staging: 11 clamped loads in flight per thread, branchless.
// Compute: row pairs, 4 MFMA chains.
// Stores: per-wave LDS transpose -> every NT store instruction writes 1KB
// lane-contiguous (full 128B output lines per instr). Theory: NT partial-line
// writes from separate instructions don't merge -> HBM RMW; this removes it.
template <bool FROMWS>
__launch_bounds__(256)
__global__ void kanconv(const float* __restrict__ x,
                        const bf16x8* __restrict__ wtab,
                        const float* __restrict__ wsp,
                        const float* __restrict__ wsi,
                        const float* __restrict__ bias,
                        float* __restrict__ out) {
    __shared__ __bf16 lds[LDSE];
    __shared__ float  sst[4 * 512];   // 2KB per wave store-transpose scratch

    const int nblk = BATCH * (HH / BY) * (WW / 64);   // 4608, %8==0
    int id = blockIdx.x;
    id = (id & 7) * (nblk / 8) + (id >> 3);           // XCD-aware swizzle (bijective)
    const int xb = id % (WW / 64);
    const int yb = (id / (WW / 64)) % (HH / BY);
    const int b  = id / ((WW / 64) * (HH / BY));
    const int y0 = yb * BY;
    const int x0 = xb * 64;
    const int tid  = threadIdx.x;
    const int lane = tid & 63;
    const int wv   = tid >> 6;

    // ---- stage input tile: rows y0-1..y0+8, cols x0-1..x0+64, 16 ch, bf16 ----
    {
        f32x4 vv[NSLOT];
#pragma unroll
        for (int it = 0; it < NSLOT; ++it) {
            int q = tid + it * 256;
            if (q > NCHUNK - 1) q = NCHUNK - 1;       // tail: safe dup address
            const int cell = q >> 2;
            const int ch4  = q & 3;
            const int c    = cell % TC;
            const int r    = cell / TC;
            const int cy   = min(max(y0 - 1 + r, 0), HH - 1);
            const int cx   = min(max(x0 - 1 + c, 0), WW - 1);
            vv[it] = *(const f32x4*)(x + ((size_t)(b * HH + cy) * WW + cx) * CINC + ch4 * 4);
        }
#pragma unroll
        for (int it = 0; it < NSLOT; ++it) {
            const int q = tid + it * 256;
            if (it < NSLOT - 1 || q < NCHUNK) {       // static for it<10
                const int cell = q >> 2;
                const int c    = cell % TC;
                const int r    = cell / TC;
                const int gy   = y0 - 1 + r;
                const int gx   = x0 - 1 + c;
                const bool ok  = ((unsigned)gy < (unsigned)HH) && ((unsigned)gx < (unsigned)WW);
                bf16x4 h;
#pragma unroll
                for (int e = 0; e < 4; ++e) h[e] = ok ? (__bf16)vv[it][e] : (__bf16)0.f;
                *(bf16x4*)&lds[q * 4] = h;
            }
        }
    }

    // ---- weight (A) fragments, 10 per wave ----
    bf16x8 aw[5][2];
#pragma unroll
    for (int s = 0; s < 5; ++s)
#pragma unroll
        for (int nt = 0; nt < 2; ++nt) {
            if (FROMWS) aw[s][nt] = wtab[(s * 2 + nt) * 64 + lane];
            else        aw[s][nt] = compute_afrag(wsp, wsi, s, nt, lane);
        }

    const int m     = lane & 15;      // B col (pixel) / D col
    const int kb    = lane >> 4;
    const int tsel  = kb >> 1;
    const int chalf = (kb & 1) * 8;
    const int sub   = wv * 16;        // x-substrip; each wave does all 8 rows
    const int bcol  = 1 + sub + m;

    int del[5];
#pragma unroll
    for (int s = 0; s < 5; ++s) {
        int tap = 2 * s + tsel;
        if (tap > 8) tap = 8;         // pad lane: A frag is 0
        del[s] = ((tap / 3 - 1) * TC + (tap % 3 - 1)) * CINC;
    }

    const f32x4 b0 = *(const f32x4*)(bias + kb * 4);
    const f32x4 b1 = *(const f32x4*)(bias + 16 + kb * 4);

    // store-transpose addressing (per-wave 512-float scratch = 16px * 32f,
    // chunk slot XOR-swizzled within each pixel to spread write banks)
    float* wsr = &sst[wv * 512];
    const int waddr0 = m * 32 + ((kb ^ (m & 7)) * 4);        // acc0 chunk kb
    const int waddr1 = m * 32 + (((kb + 4) ^ (m & 7)) * 4);  // acc1 chunk kb+4
    const int rp0 = lane >> 3;          // read pixel, instr 0 (px 0-7)
    const int rc  = lane & 7;           // read chunk
    const int raddr0 = rp0 * 32 + ((rc ^ (rp0 & 7)) * 4);
    const int rp1 = rp0 + 8;            // instr 1 (px 8-15)
    const int raddr1 = rp1 * 32 + ((rc ^ (rp1 & 7)) * 4);

    __syncthreads();

#pragma unroll
    for (int yp = 0; yp < 4; ++yp) {
        const int yi = 2 * yp;
        const int eb1 = ((1 + yi) * TC + bcol) * CINC + chalf;
        const int eb2 = eb1 + TC * CINC;
        f32x4 a0 = b0, a1 = b1;       // row yi
        f32x4 c0 = b0, c1 = b1;       // row yi+1

#pragma unroll
        for (int s = 0; s < 5; ++s) {
            bf16x8 p1 = *(const bf16x8*)&lds[eb1 + del[s]];
            bf16x8 p2 = *(const bf16x8*)&lds[eb2 + del[s]];
            a0 = __builtin_amdgcn_mfma_f32_16x16x32_bf16(aw[s][0], p1, a0, 0, 0, 0);
            c0 = __builtin_amdgcn_mfma_f32_16x16x32_bf16(aw[s][0], p2, c0, 0, 0, 0);
            a1 = __builtin_amdgcn_mfma_f32_16x16x32_bf16(aw[s][1], p1, a1, 0, 0, 0);
            c1 = __builtin_amdgcn_mfma_f32_16x16x32_bf16(aw[s][1], p2, c1, 0, 0, 0);
        }

        // ---- row yi: LDS transpose -> 2 contiguous 1KB NT stores ----
        float* g0 = out + (size_t)((b * HH + y0 + yi) * WW + x0 + sub) * FOUT;
        *(f32x4*)&wsr[waddr0] = a0;
        *(f32x4*)&wsr[waddr1] = a1;
        f32x4 r0 = *(const f32x4*)&wsr[raddr0];
        f32x4 r1 = *(const f32x4*)&wsr[raddr1];
        __builtin_nontemporal_store(r0, (f32x4*)(g0 + lane * 4));
        __builtin_nontemporal_store(r1, (f32x4*)(g0 + 256 + lane * 4));

        // ---- row yi+1 ----
        float* g1 = g0 + (size_t)WW * FOUT;
        *(f32x4*)&wsr[waddr0] = c0;
        *(f32x4*)&wsr[waddr1] = c1;
        f32x4 r2 = *(const f32x4*)&wsr[raddr0];
        f32x4 r3 = *(const f32x4*)&wsr[raddr1];
        __builtin_nontemporal_store(r2, (f32x4*)(g1 + lane * 4));
        __builtin_nontemporal_store(r3, (f32x4*)(g1 + 256 + lane * 4));
    }
}

extern "C" void kernel_launch(void* const* d_in, const int* in_sizes, int n_in,
                              void* d_out, int out_size, void* d_ws, size_t ws_size,
                              hipStream_t stream) {
    const float* x    = (const float*)d_in[0];
    const float* wsp  = (const float*)d_in[1];
    const float* wsi  = (const float*)d_in[2];
    const float* bias = (const float*)d_in[3];
    float* out        = (float*)d_out;

    const int nblk = BATCH * (HH / BY) * (WW / 64);   // 4608

    if (ws_size >= 640 * sizeof(bf16x8)) {
        bf16x8* tab = (bf16x8*)d_ws;
        prep_weights<<<3, 256, 0, stream>>>(wsp, wsi, tab);
        kanconv<true><<<nblk, 256, 0, stream>>>(x, tab, wsp, wsi, bias, out);
    } else {
        kanconv<false><<<nblk, 256, 0, stream>>>(x, nullptr, wsp, wsi, bias, out);
    }
}